// Round 2
// baseline (239.770 us; speedup 1.0000x reference)
//
#include <hip/hip_runtime.h>
#include <hip/hip_fp16.h>

#define DIM 128
#define TSH 8
#define TSZ 256    // dst-tile size (nodes per tile)
#define EBLK 4096  // edges per hist/scatter block

typedef _Float16 half8_t __attribute__((ext_vector_type(8)));
typedef float f32x4 __attribute__((ext_vector_type(4)));

// ws: hn f16[n*128] (25.6MB) | Wf f16[16384] | row_start i32[n+1] |
//     gh i32[nt*nblk] (~0.6MB) | gbsum i32[256] | tbuf u32[ne] | ebuf i32[ne]

// Per-block histogram of dst-tile key -> gh[key*nblk + block]. No global atomics.
__global__ __launch_bounds__(256) void hist_a(const int* __restrict__ dst,
                                              int* __restrict__ gh,
                                              int ne, int nblk, int nt) {
    __shared__ int h[512];
    int t = threadIdx.x;
    h[t] = 0; h[t + 256] = 0;
    __syncthreads();
    int i0 = blockIdx.x * EBLK + t;
#pragma unroll
    for (int u = 0; u < 16; ++u) {
        int i = i0 + u * 256;
        if (i < ne) atomicAdd(&h[dst[i] >> TSH], 1);
    }
    __syncthreads();
    for (int k = t; k < nt; k += 256) gh[k * nblk + blockIdx.x] = h[k];
}

// Exclusive scan of gh in 1024-chunks (4 elem/thread, shfl wave-scan);
// bsum[chunk] = chunk total. Chunk offsets folded in later at read sites.
__global__ __launch_bounds__(256) void scan_a(int* __restrict__ g,
                                              int* __restrict__ bsum, int M) {
    __shared__ int wsum[4];
    int t = threadIdx.x;
    int base = blockIdx.x * 1024 + t * 4;
    int4 v;
    if (base + 3 < M) v = *(const int4*)(g + base);
    else {
        v.x = (base + 0 < M) ? g[base + 0] : 0;
        v.y = (base + 1 < M) ? g[base + 1] : 0;
        v.z = (base + 2 < M) ? g[base + 2] : 0;
        v.w = (base + 3 < M) ? g[base + 3] : 0;
    }
    int s3 = v.x + v.y + v.z + v.w;
    int lane = t & 63, wv = t >> 6;
    int x = s3;
#pragma unroll
    for (int off = 1; off < 64; off <<= 1) {
        int y = __shfl_up(x, off, 64);
        if (lane >= off) x += y;
    }
    if (lane == 63) wsum[wv] = x;
    __syncthreads();
    int woff = 0;
    for (int i = 0; i < wv; ++i) woff += wsum[i];
    int ex = woff + x - s3;
    int4 o;
    o.x = ex; o.y = ex + v.x; o.z = o.y + v.y; o.w = o.z + v.z;
    if (base + 3 < M) *(int4*)(g + base) = o;
    else {
        if (base + 0 < M) g[base + 0] = o.x;
        if (base + 1 < M) g[base + 1] = o.y;
        if (base + 2 < M) g[base + 2] = o.z;
        if (base + 3 < M) g[base + 3] = o.w;
    }
    if (t == 0) bsum[blockIdx.x] = wsum[0] + wsum[1] + wsum[2] + wsum[3];
}

// Block 0: exclusive scan of bsum[nb] (nb<=256). Blocks 1..8: build Wf table:
// Wf[((tile*4+kk)*64+lane)*8+j] = W[tile*16+(lane&15)][kk*32+(lane>>4)*8+j]
__global__ __launch_bounds__(256) void scanb_wprep(int* __restrict__ bsum, int nb,
                                                   const float* __restrict__ W,
                                                   _Float16* __restrict__ Wf) {
    if (blockIdx.x == 0) {
        __shared__ int s[256];
        int t = threadIdx.x;
        int d = (t < nb) ? bsum[t] : 0;
        s[t] = d;
        __syncthreads();
        for (int off = 1; off < 256; off <<= 1) {
            int v = (t >= off) ? s[t - off] : 0;
            __syncthreads();
            s[t] += v;
            __syncthreads();
        }
        if (t < nb) bsum[t] = s[t] - d;
    } else {
        int idx = (blockIdx.x - 1) * 256 + threadIdx.x; // 0..2047
        int tile = idx >> 8;
        int kk = (idx >> 6) & 3;
        int lane = idx & 63;
        int nn = lane & 15, quad = lane >> 4;
        const float* wr = W + (tile * 16 + nn) * DIM + kk * 32 + quad * 8;
        _Float16* o = Wf + (size_t)idx * 8;
#pragma unroll
        for (int j = 0; j < 8; ++j) o[j] = (_Float16)wr[j];
    }
}

// Re-read edges; LDS-atomic local rank within (block,key); deterministic global
// position gh[idx]+gb[idx>>10]+rank. Write packed (src<<8)|dst_local.
__global__ __launch_bounds__(256) void scatter_b(const int* __restrict__ src,
                                                 const int* __restrict__ dst,
                                                 const int* __restrict__ gh,
                                                 const int* __restrict__ gb,
                                                 unsigned* __restrict__ tbuf,
                                                 int ne, int nblk) {
    __shared__ int h[512];
    int t = threadIdx.x;
    h[t] = 0; h[t + 256] = 0;
    __syncthreads();
    int i0 = blockIdx.x * EBLK + t;
#pragma unroll
    for (int u = 0; u < 16; ++u) {
        int i = i0 + u * 256;
        if (i < ne) {
            int d = dst[i];
            int key = d >> TSH;
            int r = atomicAdd(&h[key], 1);
            int idx = key * nblk + blockIdx.x;
            int pos = gh[idx] + gb[idx >> 10] + r;
            tbuf[pos] = ((unsigned)src[i] << TSH) | (unsigned)(d & (TSZ - 1));
        }
    }
}

// One block per tile: exact-dst LDS histogram -> LDS scan -> row_start ->
// LDS-rank scatter into final dst-sorted ebuf (values = src).
__global__ __launch_bounds__(256) void tile_sort(const unsigned* __restrict__ tbuf,
                                                 const int* __restrict__ gh,
                                                 const int* __restrict__ gb,
                                                 int* __restrict__ ebuf,
                                                 int* __restrict__ row_start,
                                                 int n, int ne, int nblk, int nt) {
    __shared__ int hist[TSZ];
    __shared__ int cur[TSZ];
    __shared__ int ps[TSZ];
    int t = threadIdx.x;
    int tile = blockIdx.x;
    int i0 = tile * nblk;
    int ts = gh[i0] + gb[i0 >> 10];
    int i1 = (tile + 1) * nblk;
    int te = (tile + 1 < nt) ? gh[i1] + gb[i1 >> 10] : ne;
    hist[t] = 0;
    __syncthreads();
    for (int i = ts + t; i < te; i += 256)
        atomicAdd(&hist[tbuf[i] & (TSZ - 1)], 1);
    __syncthreads();
    int d = hist[t];
    ps[t] = d;
    __syncthreads();
    for (int off = 1; off < 256; off <<= 1) {
        int v = (t >= off) ? ps[t - off] : 0;
        __syncthreads();
        ps[t] += v;
        __syncthreads();
    }
    int ex = ps[t] - d;
    cur[t] = ex;
    int node = tile * TSZ + t;
    if (node <= n) row_start[node] = ts + ex;
    __syncthreads();
    for (int i = ts + t; i < te; i += 256) {
        unsigned p = tbuf[i];
        int dl = (int)(p & (TSZ - 1));
        int r = atomicAdd(&cur[dl], 1);
        ebuf[ts + r] = (int)(p >> TSH);
    }
}

// hn[i][k] = (fp16) h[i][k] * rsqrt(max(deg,1)); deg from row_start diff
typedef float f32x4v __attribute__((ext_vector_type(4)));
__global__ __launch_bounds__(256) void hn_pack(const float* __restrict__ h,
                                               const int* __restrict__ rs,
                                               float2* __restrict__ hn, int n32) {
    int i = blockIdx.x * 256 + threadIdx.x;
    if (i >= n32) return;
    int node = i >> 5;
    int d = rs[node + 1] - rs[node];
    float sc = rsqrtf((float)(d > 1 ? d : 1));
    f32x4v v = __builtin_nontemporal_load((const f32x4v*)h + i);
    union { __half2 h2[2]; float2 f2; } u;
    u.h2[0] = __floats2half2_rn(v.x * sc, v.y * sc);
    u.h2[1] = __floats2half2_rn(v.z * sc, v.w * sc);
    hn[i] = u.f2;
}

// Phase 1: 32 groups x 16 lanes; group g aggregates 4 nodes {blk*128+it*32+g}
// (degree averaging over 4 draws -> balanced barrier). 16B/lane half8 gather
// loads (256B/row via 16 lanes), 16-deep unrolled -> 256B/lane in flight.
// Accumulation order = ascending edge index (unchanged vs v1 for precision).
// Phase 2: 8 waves; wave w = col-tile; 8 row-tiles x 4 chained
// mfma_f32_16x16x32_f16 (K=128), bf reused across row-tiles. NT out stores.
__global__ __launch_bounds__(512) void gather_gemm(const float2* __restrict__ hn,
                                                   const int* __restrict__ ebuf,
                                                   const int* __restrict__ rs,
                                                   const _Float16* __restrict__ Wf,
                                                   const float* __restrict__ b,
                                                   float* __restrict__ out, int n) {
    __shared__ _Float16 xs[128 * 136];
    int tid = threadIdx.x;
    int g = tid >> 4, lane = tid & 15;
    const _Float16* hp = (const _Float16*)hn + (lane << 3);

#define LD_ROW(e) (*(const half8_t*)(hp + ((size_t)(unsigned)(e) << 7)))

#pragma unroll
    for (int it = 0; it < 4; ++it) {
        int row = it * 32 + g;
        int node = blockIdx.x * 128 + row;
        half8_t acc = {(_Float16)0, (_Float16)0, (_Float16)0, (_Float16)0,
                       (_Float16)0, (_Float16)0, (_Float16)0, (_Float16)0};
        if (node < n) {
            int s0 = rs[node];
            int s1 = rs[node + 1];
            int i = s0;
            for (; i + 15 < s1; i += 16) {
                int e0 = ebuf[i +  0], e1 = ebuf[i +  1], e2 = ebuf[i +  2], e3 = ebuf[i +  3];
                int e4 = ebuf[i +  4], e5 = ebuf[i +  5], e6 = ebuf[i +  6], e7 = ebuf[i +  7];
                int e8 = ebuf[i +  8], e9 = ebuf[i +  9], ea = ebuf[i + 10], eb = ebuf[i + 11];
                int ec = ebuf[i + 12], ed = ebuf[i + 13], ee = ebuf[i + 14], ef = ebuf[i + 15];
                half8_t r0 = LD_ROW(e0), r1 = LD_ROW(e1), r2 = LD_ROW(e2), r3 = LD_ROW(e3);
                half8_t r4 = LD_ROW(e4), r5 = LD_ROW(e5), r6 = LD_ROW(e6), r7 = LD_ROW(e7);
                half8_t r8 = LD_ROW(e8), r9 = LD_ROW(e9), ra = LD_ROW(ea), rb = LD_ROW(eb);
                half8_t rc = LD_ROW(ec), rd = LD_ROW(ed), re = LD_ROW(ee), rf = LD_ROW(ef);
                acc += r0; acc += r1; acc += r2; acc += r3;
                acc += r4; acc += r5; acc += r6; acc += r7;
                acc += r8; acc += r9; acc += ra; acc += rb;
                acc += rc; acc += rd; acc += re; acc += rf;
            }
            for (; i + 3 < s1; i += 4) {
                int e0 = ebuf[i], e1 = ebuf[i + 1], e2 = ebuf[i + 2], e3 = ebuf[i + 3];
                half8_t r0 = LD_ROW(e0), r1 = LD_ROW(e1), r2 = LD_ROW(e2), r3 = LD_ROW(e3);
                acc += r0; acc += r1; acc += r2; acc += r3;
            }
            for (; i < s1; ++i) {
                half8_t r0 = LD_ROW(ebuf[i]);
                acc += r0;
            }
            int dn = s1 - s0;
            float nd = rsqrtf((float)(dn > 1 ? dn : 1));
            half8_t o;
#pragma unroll
            for (int j = 0; j < 8; ++j) o[j] = (_Float16)((float)acc[j] * nd);
            *(half8_t*)(xs + row * 136 + lane * 8) = o;
        } else {
            *(half8_t*)(xs + row * 136 + lane * 8) = acc;
        }
    }
#undef LD_ROW
    __syncthreads();

    int w = tid >> 6;     // wave = col-tile
    int wl = tid & 63;
    int cn = wl & 15;
    int quad = wl >> 4;

    f32x4 acc[8] = {{0.f, 0.f, 0.f, 0.f}, {0.f, 0.f, 0.f, 0.f},
                    {0.f, 0.f, 0.f, 0.f}, {0.f, 0.f, 0.f, 0.f},
                    {0.f, 0.f, 0.f, 0.f}, {0.f, 0.f, 0.f, 0.f},
                    {0.f, 0.f, 0.f, 0.f}, {0.f, 0.f, 0.f, 0.f}};
#pragma unroll
    for (int kk = 0; kk < 4; ++kk) {
        half8_t bf = ((const half8_t*)Wf)[(w * 4 + kk) * 64 + wl];
#pragma unroll
        for (int rt = 0; rt < 8; ++rt) {
            half8_t af = *(const half8_t*)(xs + (rt * 16 + cn) * 136 + kk * 32 + quad * 8);
            acc[rt] = __builtin_amdgcn_mfma_f32_16x16x32_f16(af, bf, acc[rt], 0, 0, 0);
        }
    }
    float bj = b[w * 16 + cn];
    int node0 = blockIdx.x * 128;
#pragma unroll
    for (int rt = 0; rt < 8; ++rt) {
#pragma unroll
        for (int r = 0; r < 4; ++r) {
            int node = node0 + rt * 16 + quad * 4 + r;
            if (node < n)
                __builtin_nontemporal_store(acc[rt][r] + bj,
                                            &out[(size_t)node * DIM + w * 16 + cn]);
        }
    }
}

extern "C" void kernel_launch(void* const* d_in, const int* in_sizes, int n_in,
                              void* d_out, int out_size, void* d_ws, size_t ws_size,
                              hipStream_t stream) {
    const float* h = (const float*)d_in[0];
    const float* W = (const float*)d_in[1];
    const float* b = (const float*)d_in[2];
    const int* esrc = (const int*)d_in[3];
    const int* edst = (const int*)d_in[4];
    float* out = (float*)d_out;

    int n = in_sizes[0] / DIM;   // 100000
    int ne = in_sizes[3];        // 1600000

    int nblk = (ne + EBLK - 1) / EBLK;    // 391
    int nt = (n + TSZ - 1) >> TSH;        // 391
    int M = nt * nblk;                    // 152881
    int nsc = (M + 1023) / 1024;          // 150

    float2* hn = (float2*)d_ws;                       // n*32 float2
    _Float16* Wf = (_Float16*)(hn + (size_t)n * 32);  // 16384 halfs
    int* row_start = (int*)(Wf + 16384);              // n+1
    int* gh = row_start + (n + 1);                    // M
    int* gbsum = gh + M;                              // 256
    unsigned* tbuf = (unsigned*)(gbsum + 256);        // ne
    int* ebuf = (int*)(tbuf + ne);                    // ne

    hist_a<<<nblk, 256, 0, stream>>>(edst, gh, ne, nblk, nt);
    scan_a<<<nsc, 256, 0, stream>>>(gh, gbsum, M);
    scanb_wprep<<<9, 256, 0, stream>>>(gbsum, nsc, W, Wf);
    scatter_b<<<nblk, 256, 0, stream>>>(esrc, edst, gh, gbsum, tbuf, ne, nblk);
    tile_sort<<<nt, 256, 0, stream>>>(tbuf, gh, gbsum, ebuf, row_start, n, ne, nblk, nt);
    hn_pack<<<(n * 32 + 255) / 256, 256, 0, stream>>>(h, row_start, hn, n * 32);
    gather_gemm<<<(n + 127) / 128, 512, 0, stream>>>(hn, ebuf, row_start, Wf, b, out, n);
}

// Round 3
// 228.097 us; speedup vs baseline: 1.0512x; 1.0512x over previous
//
#include <hip/hip_runtime.h>
#include <hip/hip_fp16.h>

#define DIM 128
#define TSH 8
#define TSZ 256    // dst-tile size (nodes per tile)
#define EBLK 4096  // edges per hist/scatter block

typedef _Float16 half8_t __attribute__((ext_vector_type(8)));
typedef float f32x4 __attribute__((ext_vector_type(4)));
typedef float f32x4v __attribute__((ext_vector_type(4)));

// ws: hn f16[n*128] (25.6MB) | Wf f16[16384] | row_start i32[n+1] |
//     gh i32[nt*nblk] (~0.6MB) | gbsum i32[256] | tbuf u32[ne] | ebuf i32[ne]

// Per-block histogram of dst-tile key -> gh[key*nblk + block]. No global atomics.
__global__ __launch_bounds__(256) void hist_a(const int* __restrict__ dst,
                                              int* __restrict__ gh,
                                              int ne, int nblk, int nt) {
    __shared__ int h[512];
    int t = threadIdx.x;
    h[t] = 0; h[t + 256] = 0;
    __syncthreads();
    int i0 = blockIdx.x * EBLK + t;
#pragma unroll
    for (int u = 0; u < 16; ++u) {
        int i = i0 + u * 256;
        if (i < ne) atomicAdd(&h[dst[i] >> TSH], 1);
    }
    __syncthreads();
    for (int k = t; k < nt; k += 256) gh[k * nblk + blockIdx.x] = h[k];
}

// Exclusive scan of gh in 1024-chunks (4 elem/thread, shfl wave-scan);
// bsum[chunk] = chunk total. Chunk offsets folded in later at read sites.
__global__ __launch_bounds__(256) void scan_a(int* __restrict__ g,
                                              int* __restrict__ bsum, int M) {
    __shared__ int wsum[4];
    int t = threadIdx.x;
    int base = blockIdx.x * 1024 + t * 4;
    int4 v;
    if (base + 3 < M) v = *(const int4*)(g + base);
    else {
        v.x = (base + 0 < M) ? g[base + 0] : 0;
        v.y = (base + 1 < M) ? g[base + 1] : 0;
        v.z = (base + 2 < M) ? g[base + 2] : 0;
        v.w = (base + 3 < M) ? g[base + 3] : 0;
    }
    int s3 = v.x + v.y + v.z + v.w;
    int lane = t & 63, wv = t >> 6;
    int x = s3;
#pragma unroll
    for (int off = 1; off < 64; off <<= 1) {
        int y = __shfl_up(x, off, 64);
        if (lane >= off) x += y;
    }
    if (lane == 63) wsum[wv] = x;
    __syncthreads();
    int woff = 0;
    for (int i = 0; i < wv; ++i) woff += wsum[i];
    int ex = woff + x - s3;
    int4 o;
    o.x = ex; o.y = ex + v.x; o.z = o.y + v.y; o.w = o.z + v.z;
    if (base + 3 < M) *(int4*)(g + base) = o;
    else {
        if (base + 0 < M) g[base + 0] = o.x;
        if (base + 1 < M) g[base + 1] = o.y;
        if (base + 2 < M) g[base + 2] = o.z;
        if (base + 3 < M) g[base + 3] = o.w;
    }
    if (t == 0) bsum[blockIdx.x] = wsum[0] + wsum[1] + wsum[2] + wsum[3];
}

// Block 0: exclusive scan of bsum[nb] (nb<=256). Blocks 1..8: build Wf table:
// Wf[((tile*4+kk)*64+lane)*8+j] = W[tile*16+(lane&15)][kk*32+(lane>>4)*8+j]
__global__ __launch_bounds__(256) void scanb_wprep(int* __restrict__ bsum, int nb,
                                                   const float* __restrict__ W,
                                                   _Float16* __restrict__ Wf) {
    if (blockIdx.x == 0) {
        __shared__ int s[256];
        int t = threadIdx.x;
        int d = (t < nb) ? bsum[t] : 0;
        s[t] = d;
        __syncthreads();
        for (int off = 1; off < 256; off <<= 1) {
            int v = (t >= off) ? s[t - off] : 0;
            __syncthreads();
            s[t] += v;
            __syncthreads();
        }
        if (t < nb) bsum[t] = s[t] - d;
    } else {
        int idx = (blockIdx.x - 1) * 256 + threadIdx.x; // 0..2047
        int tile = idx >> 8;
        int kk = (idx >> 6) & 3;
        int lane = idx & 63;
        int nn = lane & 15, quad = lane >> 4;
        const float* wr = W + (tile * 16 + nn) * DIM + kk * 32 + quad * 8;
        _Float16* o = Wf + (size_t)idx * 8;
#pragma unroll
        for (int j = 0; j < 8; ++j) o[j] = (_Float16)wr[j];
    }
}

// LDS-binned scatter. Per-key counts/bases for this block come from the scanned
// gh (no extra edge pass): cnt[k] = pos(idx+1)-pos(idx). Edges are ranked into
// LDS-sorted order (sval/skey), then written out linearly so consecutive lanes
// hit consecutive tbuf addresses within each ~10-edge key run (coalesced).
__global__ __launch_bounds__(256) void scatter_b(const int* __restrict__ src,
                                                 const int* __restrict__ dst,
                                                 const int* __restrict__ gh,
                                                 const int* __restrict__ gb,
                                                 unsigned* __restrict__ tbuf,
                                                 int ne, int nblk, int M, int nt) {
    __shared__ int h[512];            // counts -> later D[k] = gpos(k) - ps[k]
    __shared__ int ps[512];           // pair-scan workspace -> per-key excl scan
    __shared__ int cur[512];
    __shared__ unsigned sval[EBLK];   // 16KB
    __shared__ unsigned short skey[EBLK]; // 8KB
    int t = threadIdx.x;
    int blk = blockIdx.x;

    int p0a[2];
#pragma unroll
    for (int u = 0; u < 2; ++u) {
        int k = t + u * 256;
        int c = 0, p0 = 0;
        if (k < nt) {
            int idx = k * nblk + blk;
            p0 = gh[idx] + gb[idx >> 10];
            int p1 = (idx + 1 < M) ? (gh[idx + 1] + gb[(idx + 1) >> 10]) : ne;
            c = p1 - p0;
        }
        h[k] = c;
        p0a[u] = p0;
    }
    __syncthreads();
    // exclusive scan over 512 keys: pair-sum + 256-wide Hillis-Steele
    int h0 = h[2 * t];
    int s2 = h0 + h[2 * t + 1];
    ps[t] = s2;
    __syncthreads();
    for (int off = 1; off < 256; off <<= 1) {
        int v = (t >= off) ? ps[t - off] : 0;
        __syncthreads();
        ps[t] += v;
        __syncthreads();
    }
    int inc = ps[t];
    __syncthreads();
    int ex0 = inc - s2;
    ps[2 * t] = ex0;
    ps[2 * t + 1] = ex0 + h0;
    cur[2 * t] = ex0;
    cur[2 * t + 1] = ex0 + h0;
    __syncthreads();
#pragma unroll
    for (int u = 0; u < 2; ++u) {
        int k = t + u * 256;
        h[k] = p0a[u] - ps[k];   // D[k]: lds-pos p -> global pos D[k]+p
    }
    __syncthreads();

    int i0 = blk * EBLK + t;
#pragma unroll
    for (int u = 0; u < 16; ++u) {
        int i = i0 + u * 256;
        if (i < ne) {
            int d = dst[i];
            int key = d >> TSH;
            int r = atomicAdd(&cur[key], 1);
            sval[r] = ((unsigned)src[i] << TSH) | (unsigned)(d & (TSZ - 1));
            skey[r] = (unsigned short)key;
        }
    }
    __syncthreads();
    int cnt = ne - blk * EBLK;
    if (cnt > EBLK) cnt = EBLK;
    for (int p = t; p < cnt; p += 256)
        tbuf[h[skey[p]] + p] = sval[p];
}

// One block per tile: exact-dst LDS histogram -> LDS scan -> row_start ->
// LDS-rank scatter into final dst-sorted ebuf (values = src).
__global__ __launch_bounds__(256) void tile_sort(const unsigned* __restrict__ tbuf,
                                                 const int* __restrict__ gh,
                                                 const int* __restrict__ gb,
                                                 int* __restrict__ ebuf,
                                                 int* __restrict__ row_start,
                                                 int n, int ne, int nblk, int nt) {
    __shared__ int hist[TSZ];
    __shared__ int cur[TSZ];
    __shared__ int ps[TSZ];
    int t = threadIdx.x;
    int tile = blockIdx.x;
    int i0 = tile * nblk;
    int ts = gh[i0] + gb[i0 >> 10];
    int i1 = (tile + 1) * nblk;
    int te = (tile + 1 < nt) ? gh[i1] + gb[i1 >> 10] : ne;
    hist[t] = 0;
    __syncthreads();
    for (int i = ts + t; i < te; i += 256)
        atomicAdd(&hist[tbuf[i] & (TSZ - 1)], 1);
    __syncthreads();
    int d = hist[t];
    ps[t] = d;
    __syncthreads();
    for (int off = 1; off < 256; off <<= 1) {
        int v = (t >= off) ? ps[t - off] : 0;
        __syncthreads();
        ps[t] += v;
        __syncthreads();
    }
    int ex = ps[t] - d;
    cur[t] = ex;
    int node = tile * TSZ + t;
    if (node <= n) row_start[node] = ts + ex;
    __syncthreads();
    for (int i = ts + t; i < te; i += 256) {
        unsigned p = tbuf[i];
        int dl = (int)(p & (TSZ - 1));
        int r = atomicAdd(&cur[dl], 1);
        ebuf[ts + r] = (int)(p >> TSH);
    }
}

// hn[i][k] = (fp16) h[i][k] * rsqrt(max(deg,1)); deg from row_start diff
__global__ __launch_bounds__(256) void hn_pack(const float* __restrict__ h,
                                               const int* __restrict__ rs,
                                               float2* __restrict__ hn, int n32) {
    int i = blockIdx.x * 256 + threadIdx.x;
    if (i >= n32) return;
    int node = i >> 5;
    int d = rs[node + 1] - rs[node];
    float sc = rsqrtf((float)(d > 1 ? d : 1));
    f32x4v v = __builtin_nontemporal_load((const f32x4v*)h + i);
    union { __half2 h2[2]; float2 f2; } u;
    u.h2[0] = __floats2half2_rn(v.x * sc, v.y * sc);
    u.h2[1] = __floats2half2_rn(v.z * sc, v.w * sc);
    hn[i] = u.f2;
}

// Phase 1: 16 groups x 32 lanes; group g aggregates 4 nodes {blk*64+it*16+g}
// (degree averaging over 4 draws -> balanced barrier), x8-unrolled loads.
// Round-1 showed deeper MLP does NOT raise BW (fabric-bound at ~3.2TB/s random
// lines), so this is the round-0 proven structure. NT stores for out.
// Phase 2: 8 waves; wave w = col-tile; 4 row-tiles x 4 chained
// mfma_f32_16x16x32_f16 (K=128), bf reused across row-tiles.
__global__ __launch_bounds__(512) void gather_gemm(const float2* __restrict__ hn,
                                                   const int* __restrict__ ebuf,
                                                   const int* __restrict__ rs,
                                                   const _Float16* __restrict__ Wf,
                                                   const float* __restrict__ b,
                                                   float* __restrict__ out, int n) {
    __shared__ _Float16 xs[64 * 136];
    int tid = threadIdx.x;
    int g = tid >> 5, lane = tid & 31;

#pragma unroll
    for (int it = 0; it < 4; ++it) {
        int row = it * 16 + g;
        int node = blockIdx.x * 64 + row;
        union { __half2 h2[2]; float2 f2; } u;
        if (node < n) {
            int s0 = rs[node];
            int s1 = rs[node + 1];
            __half2 a0 = __floats2half2_rn(0.f, 0.f), a1 = a0;
            int i = s0;
            for (; i + 7 < s1; i += 8) {
                int e0 = ebuf[i], e1 = ebuf[i + 1], e2 = ebuf[i + 2], e3 = ebuf[i + 3];
                int e4 = ebuf[i + 4], e5 = ebuf[i + 5], e6 = ebuf[i + 6], e7 = ebuf[i + 7];
                float2 r0 = hn[(size_t)e0 * 32 + lane];
                float2 r1 = hn[(size_t)e1 * 32 + lane];
                float2 r2 = hn[(size_t)e2 * 32 + lane];
                float2 r3 = hn[(size_t)e3 * 32 + lane];
                float2 r4 = hn[(size_t)e4 * 32 + lane];
                float2 r5 = hn[(size_t)e5 * 32 + lane];
                float2 r6 = hn[(size_t)e6 * 32 + lane];
                float2 r7 = hn[(size_t)e7 * 32 + lane];
                const __half2* q0 = (const __half2*)&r0;
                const __half2* q1 = (const __half2*)&r1;
                const __half2* q2 = (const __half2*)&r2;
                const __half2* q3 = (const __half2*)&r3;
                const __half2* q4 = (const __half2*)&r4;
                const __half2* q5 = (const __half2*)&r5;
                const __half2* q6 = (const __half2*)&r6;
                const __half2* q7 = (const __half2*)&r7;
                a0 = __hadd2(a0, q0[0]); a1 = __hadd2(a1, q0[1]);
                a0 = __hadd2(a0, q1[0]); a1 = __hadd2(a1, q1[1]);
                a0 = __hadd2(a0, q2[0]); a1 = __hadd2(a1, q2[1]);
                a0 = __hadd2(a0, q3[0]); a1 = __hadd2(a1, q3[1]);
                a0 = __hadd2(a0, q4[0]); a1 = __hadd2(a1, q4[1]);
                a0 = __hadd2(a0, q5[0]); a1 = __hadd2(a1, q5[1]);
                a0 = __hadd2(a0, q6[0]); a1 = __hadd2(a1, q6[1]);
                a0 = __hadd2(a0, q7[0]); a1 = __hadd2(a1, q7[1]);
            }
            for (; i + 3 < s1; i += 4) {
                int e0 = ebuf[i], e1 = ebuf[i + 1], e2 = ebuf[i + 2], e3 = ebuf[i + 3];
                float2 r0 = hn[(size_t)e0 * 32 + lane];
                float2 r1 = hn[(size_t)e1 * 32 + lane];
                float2 r2 = hn[(size_t)e2 * 32 + lane];
                float2 r3 = hn[(size_t)e3 * 32 + lane];
                const __half2* q0 = (const __half2*)&r0;
                const __half2* q1 = (const __half2*)&r1;
                const __half2* q2 = (const __half2*)&r2;
                const __half2* q3 = (const __half2*)&r3;
                a0 = __hadd2(a0, q0[0]); a1 = __hadd2(a1, q0[1]);
                a0 = __hadd2(a0, q1[0]); a1 = __hadd2(a1, q1[1]);
                a0 = __hadd2(a0, q2[0]); a1 = __hadd2(a1, q2[1]);
                a0 = __hadd2(a0, q3[0]); a1 = __hadd2(a1, q3[1]);
            }
            for (; i < s1; ++i) {
                int e0 = ebuf[i];
                float2 r0 = hn[(size_t)e0 * 32 + lane];
                const __half2* q0 = (const __half2*)&r0;
                a0 = __hadd2(a0, q0[0]); a1 = __hadd2(a1, q0[1]);
            }
            int dn = s1 - s0;
            float nd = rsqrtf((float)(dn > 1 ? dn : 1));
            float2 f0 = __half22float2(a0), f1 = __half22float2(a1);
            u.h2[0] = __floats2half2_rn(f0.x * nd, f0.y * nd);
            u.h2[1] = __floats2half2_rn(f1.x * nd, f1.y * nd);
        } else {
            u.h2[0] = __floats2half2_rn(0.f, 0.f);
            u.h2[1] = u.h2[0];
        }
        *(float2*)(xs + row * 136 + lane * 4) = u.f2;
    }
    __syncthreads();

    int w = tid >> 6;     // wave = col-tile
    int wl = tid & 63;
    int cn = wl & 15;
    int quad = wl >> 4;

    f32x4 acc[4] = {{0.f, 0.f, 0.f, 0.f}, {0.f, 0.f, 0.f, 0.f},
                    {0.f, 0.f, 0.f, 0.f}, {0.f, 0.f, 0.f, 0.f}};
#pragma unroll
    for (int kk = 0; kk < 4; ++kk) {
        half8_t bf = ((const half8_t*)Wf)[(w * 4 + kk) * 64 + wl];
#pragma unroll
        for (int rt = 0; rt < 4; ++rt) {
            half8_t af = *(const half8_t*)(xs + (rt * 16 + cn) * 136 + kk * 32 + quad * 8);
            acc[rt] = __builtin_amdgcn_mfma_f32_16x16x32_f16(af, bf, acc[rt], 0, 0, 0);
        }
    }
    float bj = b[w * 16 + cn];
    int node0 = blockIdx.x * 64;
#pragma unroll
    for (int rt = 0; rt < 4; ++rt) {
#pragma unroll
        for (int r = 0; r < 4; ++r) {
            int node = node0 + rt * 16 + quad * 4 + r;
            if (node < n)
                __builtin_nontemporal_store(acc[rt][r] + bj,
                                            &out[(size_t)node * DIM + w * 16 + cn]);
        }
    }
}

extern "C" void kernel_launch(void* const* d_in, const int* in_sizes, int n_in,
                              void* d_out, int out_size, void* d_ws, size_t ws_size,
                              hipStream_t stream) {
    const float* h = (const float*)d_in[0];
    const float* W = (const float*)d_in[1];
    const float* b = (const float*)d_in[2];
    const int* esrc = (const int*)d_in[3];
    const int* edst = (const int*)d_in[4];
    float* out = (float*)d_out;

    int n = in_sizes[0] / DIM;   // 100000
    int ne = in_sizes[3];        // 1600000

    int nblk = (ne + EBLK - 1) / EBLK;    // 391
    int nt = (n + TSZ - 1) >> TSH;        // 391
    int M = nt * nblk;                    // 152881
    int nsc = (M + 1023) / 1024;          // 150

    float2* hn = (float2*)d_ws;                       // n*32 float2
    _Float16* Wf = (_Float16*)(hn + (size_t)n * 32);  // 16384 halfs
    int* row_start = (int*)(Wf + 16384);              // n+1
    int* gh = row_start + (n + 1);                    // M
    int* gbsum = gh + M;                              // 256
    unsigned* tbuf = (unsigned*)(gbsum + 256);        // ne
    int* ebuf = (int*)(tbuf + ne);                    // ne

    hist_a<<<nblk, 256, 0, stream>>>(edst, gh, ne, nblk, nt);
    scan_a<<<nsc, 256, 0, stream>>>(gh, gbsum, M);
    scanb_wprep<<<9, 256, 0, stream>>>(gbsum, nsc, W, Wf);
    scatter_b<<<nblk, 256, 0, stream>>>(esrc, edst, gh, gbsum, tbuf, ne, nblk, M, nt);
    tile_sort<<<nt, 256, 0, stream>>>(tbuf, gh, gbsum, ebuf, row_start, n, ne, nblk, nt);
    hn_pack<<<(n * 32 + 255) / 256, 256, 0, stream>>>(h, row_start, hn, n * 32);
    gather_gemm<<<(n + 63) / 64, 512, 0, stream>>>(hn, ebuf, row_start, Wf, b, out, n);
}

// Round 4
// 216.381 us; speedup vs baseline: 1.1081x; 1.0541x over previous
//
#include <hip/hip_runtime.h>
#include <hip/hip_fp16.h>

#define DIM 128
#define TSH 8
#define TSZ 256    // dst-tile size (nodes per tile)
#define EBLK 4096  // edges per hist/scatter block

typedef _Float16 half8_t __attribute__((ext_vector_type(8)));
typedef float f32x4 __attribute__((ext_vector_type(4)));
typedef float f32x4v __attribute__((ext_vector_type(4)));

// ws: hn f16[n*128] (25.6MB) | Wf f16[16384] | row_start i32[n+1] |
//     gh i32[nt*nblk] (~0.6MB) | gbsum i32[256] | tbuf u32[ne] | ebuf i32[ne]
// Assumptions baked in: nt <= 512, nsc <= 256 (n=100000, ne=1.6M -> nt=391, nsc=150)

// Blocks [0,nblk): per-block histogram of dst-tile key -> gh[key*nblk+block].
// Blocks [nblk,nblk+2): build Wf table (was scanb_wprep's job):
// Wf[((tile*4+kk)*64+lane)*8+j] = W[tile*16+(lane&15)][kk*32+(lane>>4)*8+j]
__global__ __launch_bounds__(1024) void hist_a(const int* __restrict__ dst,
                                               int* __restrict__ gh,
                                               int ne, int nblk, int nt,
                                               const float* __restrict__ W,
                                               _Float16* __restrict__ Wf) {
    __shared__ int h[512];
    int t = threadIdx.x;
    int blk = blockIdx.x;
    if (blk >= nblk) {
        int idx = (blk - nblk) * 1024 + t;  // 0..2047
        int tile = idx >> 8;
        int kk = (idx >> 6) & 3;
        int lane = idx & 63;
        int nn = lane & 15, quad = lane >> 4;
        const float* wr = W + (tile * 16 + nn) * DIM + kk * 32 + quad * 8;
        _Float16* o = Wf + (size_t)idx * 8;
#pragma unroll
        for (int j = 0; j < 8; ++j) o[j] = (_Float16)wr[j];
        return;
    }
    if (t < 512) h[t] = 0;
    __syncthreads();
    int i0 = blk * EBLK + t;
#pragma unroll
    for (int u = 0; u < 4; ++u) {
        int i = i0 + u * 1024;
        if (i < ne) atomicAdd(&h[dst[i] >> TSH], 1);
    }
    __syncthreads();
    for (int k = t; k < nt; k += 1024) gh[k * nblk + blk] = h[k];
}

// Exclusive scan of gh in 1024-chunks (4 elem/thread, shfl wave-scan);
// bsum[chunk] = raw chunk total (scanned locally by consumers).
__global__ __launch_bounds__(256) void scan_a(int* __restrict__ g,
                                              int* __restrict__ bsum, int M) {
    __shared__ int wsum[4];
    int t = threadIdx.x;
    int base = blockIdx.x * 1024 + t * 4;
    int4 v;
    if (base + 3 < M) v = *(const int4*)(g + base);
    else {
        v.x = (base + 0 < M) ? g[base + 0] : 0;
        v.y = (base + 1 < M) ? g[base + 1] : 0;
        v.z = (base + 2 < M) ? g[base + 2] : 0;
        v.w = (base + 3 < M) ? g[base + 3] : 0;
    }
    int s3 = v.x + v.y + v.z + v.w;
    int lane = t & 63, wv = t >> 6;
    int x = s3;
#pragma unroll
    for (int off = 1; off < 64; off <<= 1) {
        int y = __shfl_up(x, off, 64);
        if (lane >= off) x += y;
    }
    if (lane == 63) wsum[wv] = x;
    __syncthreads();
    int woff = 0;
    for (int i = 0; i < wv; ++i) woff += wsum[i];
    int ex = woff + x - s3;
    int4 o;
    o.x = ex; o.y = ex + v.x; o.z = o.y + v.y; o.w = o.z + v.z;
    if (base + 3 < M) *(int4*)(g + base) = o;
    else {
        if (base + 0 < M) g[base + 0] = o.x;
        if (base + 1 < M) g[base + 1] = o.y;
        if (base + 2 < M) g[base + 2] = o.z;
        if (base + 3 < M) g[base + 3] = o.w;
    }
    if (t == 0) bsum[blockIdx.x] = wsum[0] + wsum[1] + wsum[2] + wsum[3];
}

// LDS-binned scatter (coalesced tbuf writes). Local 256-wide scan of bsum
// replaces the old scanb kernel; per-key counts from scanned gh.
__global__ __launch_bounds__(1024) void scatter_b(const int* __restrict__ src,
                                                  const int* __restrict__ dst,
                                                  const int* __restrict__ gh,
                                                  const int* __restrict__ bsum,
                                                  unsigned* __restrict__ tbuf,
                                                  int ne, int nblk, int M, int nt,
                                                  int nsc) {
    __shared__ int hD[512];
    __shared__ int ps[256];
    __shared__ int cur[512];
    __shared__ int gbl[256];
    __shared__ unsigned sval[EBLK];        // 16KB
    __shared__ unsigned short skey[EBLK];  // 8KB
    int t = threadIdx.x, blk = blockIdx.x;

    // local exclusive scan of bsum[0..nsc)
    int bd = 0;
    if (t < 256) { bd = (t < nsc) ? bsum[t] : 0; ps[t] = bd; }
    __syncthreads();
    for (int off = 1; off < 256; off <<= 1) {
        int v = (t < 256 && t >= off) ? ps[t - off] : 0;
        __syncthreads();
        if (t < 256) ps[t] += v;
        __syncthreads();
    }
    if (t < 256) gbl[t] = ps[t] - bd;
    __syncthreads();

    // per-key global base p0 and count c for this block
    int p0 = 0, c = 0;
    if (t < 512) {
        if (t < nt) {
            int idx = t * nblk + blk;
            p0 = gh[idx] + gbl[idx >> 10];
            int p1 = (idx + 1 < M) ? (gh[idx + 1] + gbl[(idx + 1) >> 10]) : ne;
            c = p1 - p0;
        }
        hD[t] = c;
    }
    __syncthreads();
    // exclusive scan over 512 keys: pair-sum + masked 256-wide Hillis-Steele
    int h0 = 0, h1 = 0;
    if (t < 256) { h0 = hD[2 * t]; h1 = hD[2 * t + 1]; ps[t] = h0 + h1; }
    __syncthreads();
    for (int off = 1; off < 256; off <<= 1) {
        int v = (t < 256 && t >= off) ? ps[t - off] : 0;
        __syncthreads();
        if (t < 256) ps[t] += v;
        __syncthreads();
    }
    if (t < 256) {
        int ex0 = ps[t] - h0 - h1;
        cur[2 * t] = ex0;
        cur[2 * t + 1] = ex0 + h0;
    }
    __syncthreads();
    if (t < 512) hD[t] = p0 - cur[t];   // D[k]: lds-pos p -> global pos D[k]+p
    __syncthreads();

    int i0 = blk * EBLK + t;
#pragma unroll
    for (int u = 0; u < 4; ++u) {
        int i = i0 + u * 1024;
        if (i < ne) {
            int d = dst[i];
            int key = d >> TSH;
            int r = atomicAdd(&cur[key], 1);
            sval[r] = ((unsigned)src[i] << TSH) | (unsigned)(d & (TSZ - 1));
            skey[r] = (unsigned short)key;
        }
    }
    __syncthreads();
    int cnt = ne - blk * EBLK;
    if (cnt > EBLK) cnt = EBLK;
    for (int p = t; p < cnt; p += 1024)
        tbuf[hD[skey[p]] + p] = sval[p];
}

// One block per tile: exact-dst LDS histogram -> scan -> row_start ->
// LDS-rank scatter into dst-sorted ebuf; FUSED hn pack (deg = tile hist,
// h rows of the tile are contiguous -> coalesced stream).
__global__ __launch_bounds__(1024) void tile_sort(const unsigned* __restrict__ tbuf,
                                                  const int* __restrict__ gh,
                                                  const int* __restrict__ bsum,
                                                  int* __restrict__ ebuf,
                                                  int* __restrict__ row_start,
                                                  const float* __restrict__ hsrc,
                                                  float2* __restrict__ hn,
                                                  int n, int ne, int nblk, int nt,
                                                  int nsc) {
    __shared__ int hist[TSZ];
    __shared__ int cur[TSZ];
    __shared__ int ps[256];
    __shared__ int gbl[256];
    __shared__ float scl[TSZ];
    int t = threadIdx.x;
    int tile = blockIdx.x;

    int bd = 0;
    if (t < 256) { bd = (t < nsc) ? bsum[t] : 0; ps[t] = bd; hist[t] = 0; }
    __syncthreads();
    for (int off = 1; off < 256; off <<= 1) {
        int v = (t < 256 && t >= off) ? ps[t - off] : 0;
        __syncthreads();
        if (t < 256) ps[t] += v;
        __syncthreads();
    }
    if (t < 256) gbl[t] = ps[t] - bd;
    __syncthreads();

    int i0 = tile * nblk;
    int ts = gh[i0] + gbl[i0 >> 10];
    int i1 = (tile + 1) * nblk;
    int te = (tile + 1 < nt) ? gh[i1] + gbl[i1 >> 10] : ne;

    for (int i = ts + t; i < te; i += 1024)
        atomicAdd(&hist[tbuf[i] & (TSZ - 1)], 1);
    __syncthreads();
    int d = 0;
    if (t < 256) { d = hist[t]; ps[t] = d; }
    __syncthreads();
    for (int off = 1; off < 256; off <<= 1) {
        int v = (t < 256 && t >= off) ? ps[t - off] : 0;
        __syncthreads();
        if (t < 256) ps[t] += v;
        __syncthreads();
    }
    if (t < 256) {
        int ex = ps[t] - d;
        cur[t] = ex;
        int node = tile * TSZ + t;
        if (node <= n) row_start[node] = ts + ex;
        scl[t] = rsqrtf((float)(d > 1 ? d : 1));
    }
    __syncthreads();
    for (int i = ts + t; i < te; i += 1024) {
        unsigned p = tbuf[i];
        int dl = (int)(p & (TSZ - 1));
        int r = atomicAdd(&cur[dl], 1);
        ebuf[ts + r] = (int)(p >> TSH);
    }
    // fused hn pack: 256 nodes x 32 float4 = 8192 elems, coalesced
    int qbase = tile * 8192;
    for (int q = t; q < 8192; q += 1024) {
        int node = tile * TSZ + (q >> 5);
        if (node < n) {
            f32x4v v = __builtin_nontemporal_load((const f32x4v*)hsrc + qbase + q);
            float sc = scl[q >> 5];
            union { __half2 h2[2]; float2 f2; } u;
            u.h2[0] = __floats2half2_rn(v.x * sc, v.y * sc);
            u.h2[1] = __floats2half2_rn(v.z * sc, v.w * sc);
            hn[qbase + q] = u.f2;
        }
    }
}

// Phase 1: 16 groups x 32 lanes; group g aggregates 4 nodes {blk*64+it*16+g}
// (degree averaging over 4 draws -> balanced barrier), x8-unrolled loads.
// Fabric-bound at ~3.2TB/s random lines (round-1 A/B) -> proven structure kept.
// Phase 2: 8 waves; wave w = col-tile; 4 row-tiles x 4 chained
// mfma_f32_16x16x32_f16 (K=128), bf reused across row-tiles. NT out stores.
__global__ __launch_bounds__(512) void gather_gemm(const float2* __restrict__ hn,
                                                   const int* __restrict__ ebuf,
                                                   const int* __restrict__ rs,
                                                   const _Float16* __restrict__ Wf,
                                                   const float* __restrict__ b,
                                                   float* __restrict__ out, int n) {
    __shared__ _Float16 xs[64 * 136];
    int tid = threadIdx.x;
    int g = tid >> 5, lane = tid & 31;

#pragma unroll
    for (int it = 0; it < 4; ++it) {
        int row = it * 16 + g;
        int node = blockIdx.x * 64 + row;
        union { __half2 h2[2]; float2 f2; } u;
        if (node < n) {
            int s0 = rs[node];
            int s1 = rs[node + 1];
            __half2 a0 = __floats2half2_rn(0.f, 0.f), a1 = a0;
            int i = s0;
            for (; i + 7 < s1; i += 8) {
                int e0 = ebuf[i], e1 = ebuf[i + 1], e2 = ebuf[i + 2], e3 = ebuf[i + 3];
                int e4 = ebuf[i + 4], e5 = ebuf[i + 5], e6 = ebuf[i + 6], e7 = ebuf[i + 7];
                float2 r0 = hn[(size_t)e0 * 32 + lane];
                float2 r1 = hn[(size_t)e1 * 32 + lane];
                float2 r2 = hn[(size_t)e2 * 32 + lane];
                float2 r3 = hn[(size_t)e3 * 32 + lane];
                float2 r4 = hn[(size_t)e4 * 32 + lane];
                float2 r5 = hn[(size_t)e5 * 32 + lane];
                float2 r6 = hn[(size_t)e6 * 32 + lane];
                float2 r7 = hn[(size_t)e7 * 32 + lane];
                const __half2* q0 = (const __half2*)&r0;
                const __half2* q1 = (const __half2*)&r1;
                const __half2* q2 = (const __half2*)&r2;
                const __half2* q3 = (const __half2*)&r3;
                const __half2* q4 = (const __half2*)&r4;
                const __half2* q5 = (const __half2*)&r5;
                const __half2* q6 = (const __half2*)&r6;
                const __half2* q7 = (const __half2*)&r7;
                a0 = __hadd2(a0, q0[0]); a1 = __hadd2(a1, q0[1]);
                a0 = __hadd2(a0, q1[0]); a1 = __hadd2(a1, q1[1]);
                a0 = __hadd2(a0, q2[0]); a1 = __hadd2(a1, q2[1]);
                a0 = __hadd2(a0, q3[0]); a1 = __hadd2(a1, q3[1]);
                a0 = __hadd2(a0, q4[0]); a1 = __hadd2(a1, q4[1]);
                a0 = __hadd2(a0, q5[0]); a1 = __hadd2(a1, q5[1]);
                a0 = __hadd2(a0, q6[0]); a1 = __hadd2(a1, q6[1]);
                a0 = __hadd2(a0, q7[0]); a1 = __hadd2(a1, q7[1]);
            }
            for (; i + 3 < s1; i += 4) {
                int e0 = ebuf[i], e1 = ebuf[i + 1], e2 = ebuf[i + 2], e3 = ebuf[i + 3];
                float2 r0 = hn[(size_t)e0 * 32 + lane];
                float2 r1 = hn[(size_t)e1 * 32 + lane];
                float2 r2 = hn[(size_t)e2 * 32 + lane];
                float2 r3 = hn[(size_t)e3 * 32 + lane];
                const __half2* q0 = (const __half2*)&r0;
                const __half2* q1 = (const __half2*)&r1;
                const __half2* q2 = (const __half2*)&r2;
                const __half2* q3 = (const __half2*)&r3;
                a0 = __hadd2(a0, q0[0]); a1 = __hadd2(a1, q0[1]);
                a0 = __hadd2(a0, q1[0]); a1 = __hadd2(a1, q1[1]);
                a0 = __hadd2(a0, q2[0]); a1 = __hadd2(a1, q2[1]);
                a0 = __hadd2(a0, q3[0]); a1 = __hadd2(a1, q3[1]);
            }
            for (; i < s1; ++i) {
                int e0 = ebuf[i];
                float2 r0 = hn[(size_t)e0 * 32 + lane];
                const __half2* q0 = (const __half2*)&r0;
                a0 = __hadd2(a0, q0[0]); a1 = __hadd2(a1, q0[1]);
            }
            int dn = s1 - s0;
            float nd = rsqrtf((float)(dn > 1 ? dn : 1));
            float2 f0 = __half22float2(a0), f1 = __half22float2(a1);
            u.h2[0] = __floats2half2_rn(f0.x * nd, f0.y * nd);
            u.h2[1] = __floats2half2_rn(f1.x * nd, f1.y * nd);
        } else {
            u.h2[0] = __floats2half2_rn(0.f, 0.f);
            u.h2[1] = u.h2[0];
        }
        *(float2*)(xs + row * 136 + lane * 4) = u.f2;
    }
    __syncthreads();

    int w = tid >> 6;     // wave = col-tile
    int wl = tid & 63;
    int cn = wl & 15;
    int quad = wl >> 4;

    f32x4 acc[4] = {{0.f, 0.f, 0.f, 0.f}, {0.f, 0.f, 0.f, 0.f},
                    {0.f, 0.f, 0.f, 0.f}, {0.f, 0.f, 0.f, 0.f}};
#pragma unroll
    for (int kk = 0; kk < 4; ++kk) {
        half8_t bf = ((const half8_t*)Wf)[(w * 4 + kk) * 64 + wl];
#pragma unroll
        for (int rt = 0; rt < 4; ++rt) {
            half8_t af = *(const half8_t*)(xs + (rt * 16 + cn) * 136 + kk * 32 + quad * 8);
            acc[rt] = __builtin_amdgcn_mfma_f32_16x16x32_f16(af, bf, acc[rt], 0, 0, 0);
        }
    }
    float bj = b[w * 16 + cn];
    int node0 = blockIdx.x * 64;
#pragma unroll
    for (int rt = 0; rt < 4; ++rt) {
#pragma unroll
        for (int r = 0; r < 4; ++r) {
            int node = node0 + rt * 16 + quad * 4 + r;
            if (node < n)
                __builtin_nontemporal_store(acc[rt][r] + bj,
                                            &out[(size_t)node * DIM + w * 16 + cn]);
        }
    }
}

extern "C" void kernel_launch(void* const* d_in, const int* in_sizes, int n_in,
                              void* d_out, int out_size, void* d_ws, size_t ws_size,
                              hipStream_t stream) {
    const float* h = (const float*)d_in[0];
    const float* W = (const float*)d_in[1];
    const float* b = (const float*)d_in[2];
    const int* esrc = (const int*)d_in[3];
    const int* edst = (const int*)d_in[4];
    float* out = (float*)d_out;

    int n = in_sizes[0] / DIM;   // 100000
    int ne = in_sizes[3];        // 1600000

    int nblk = (ne + EBLK - 1) / EBLK;    // 391
    int nt = (n + TSZ - 1) >> TSH;        // 391
    int M = nt * nblk;                    // 152881
    int nsc = (M + 1023) / 1024;          // 150

    float2* hn = (float2*)d_ws;                       // n*32 float2
    _Float16* Wf = (_Float16*)(hn + (size_t)n * 32);  // 16384 halfs
    int* row_start = (int*)(Wf + 16384);              // n+1
    int* gh = row_start + (n + 1);                    // M
    int* gbsum = gh + M;                              // 256
    unsigned* tbuf = (unsigned*)(gbsum + 256);        // ne
    int* ebuf = (int*)(tbuf + ne);                    // ne

    hist_a<<<nblk + 2, 1024, 0, stream>>>(edst, gh, ne, nblk, nt, W, Wf);
    scan_a<<<nsc, 256, 0, stream>>>(gh, gbsum, M);
    scatter_b<<<nblk, 1024, 0, stream>>>(esrc, edst, gh, gbsum, tbuf, ne, nblk, M, nt, nsc);
    tile_sort<<<nt, 1024, 0, stream>>>(tbuf, gh, gbsum, ebuf, row_start, h, hn, n, ne, nblk, nt, nsc);
    gather_gemm<<<(n + 63) / 64, 512, 0, stream>>>(hn, ebuf, row_start, Wf, b, out, n);
}